// Round 11
// baseline (362.425 us; speedup 1.0000x reference)
//
#include <hip/hip_runtime.h>
#include <cstdint>
#include <cstddef>

// Problem constants (B=1, S=4096, H=1024, 16 heads x 64)
#define S_LEN 4096
#define NHEADS 16
#define HD 64
#define HDIM 1024

typedef _Float16 f16x8 __attribute__((ext_vector_type(8)));
typedef _Float16 f16x4 __attribute__((ext_vector_type(4)));
typedef __fp16 h16x2 __attribute__((ext_vector_type(2)));   // cvt_pkrtz native
typedef float f32x4 __attribute__((ext_vector_type(4)));
typedef unsigned char uchar;
typedef unsigned int u32;

__device__ __forceinline__ f32x4 mfma16h(f16x8 a, f16x8 b, f32x4 c) {
    return __builtin_amdgcn_mfma_f32_16x16x32_f16(a, b, c, 0, 0, 0);
}
// async global->LDS, 16B/lane; lds must be wave-uniform base (HW adds lane*16)
__device__ __forceinline__ void async16(void* lds, const void* g) {
    __builtin_amdgcn_global_load_lds(
        (const __attribute__((address_space(1))) u32*)g,
        (__attribute__((address_space(3))) u32*)lds, 16, 0, 0);
}

// ---------------------------------------------------------------------------
// Packed fp16 format: per 64-elem logical row, a 128B record of 8 x 16B
// blocks XOR-swizzled: element e of row r lives at ((e>>3)^(r&7))*16+(e&7)*2.
// Byte layout == LDS image -> staging is straight 16B async copies.
// ---------------------------------------------------------------------------

// x [4096][1024] fp32 -> Xp [m][kc=16][128B]; also emits fp16 key flags {0,1}
__global__ __launch_bounds__(256) void pack_x(const float* __restrict__ X,
                                              uchar* __restrict__ P,
                                              const int* __restrict__ M,
                                              _Float16* __restrict__ FM16)
{
    int id = blockIdx.x * 256 + threadIdx.x;       // 4096*128
    int m = id >> 7, g = id & 127;
    int kc = g >> 3, b = g & 7;
    float v[8];
    *(float4*)&v[0] = *(const float4*)&X[(size_t)m * HDIM + kc * 64 + b * 8];
    *(float4*)&v[4] = *(const float4*)&X[(size_t)m * HDIM + kc * 64 + b * 8 + 4];
    __align__(16) _Float16 h[8];
    #pragma unroll
    for (int i = 0; i < 8; i++) h[i] = (_Float16)v[i];
    size_t base = ((size_t)(m * 16 + kc)) * 128 + (size_t)((b ^ (m & 7)) * 16);
    *(uint4*)(P + base) = *(const uint4*)h;
    if (id < S_LEN) FM16[id] = (_Float16)((M[id] == 0) ? 0.0f : 1.0f);
}

// All 4 weight matrices [1024 k][1024 n] fp32 -> fp16 B^T rows [n][kc=16][128B]
__global__ __launch_bounds__(256) void pack_w4(
    const float* __restrict__ W0, const float* __restrict__ W1,
    const float* __restrict__ W2, const float* __restrict__ W3,
    uchar* __restrict__ P)
{
    int id = blockIdx.x * 256 + threadIdx.x;       // 4*128*1024
    int wsel = id >> 17;
    int lid  = id & 131071;
    int g = lid >> 10, n = lid & 1023;
    int kc = g >> 3, b = g & 7;
    const float* W = (wsel == 0) ? W0 : (wsel == 1) ? W1 : (wsel == 2) ? W2 : W3;
    uchar* dst = P + (size_t)wsel * 2097152;
    float v[8];
    #pragma unroll
    for (int j = 0; j < 8; j++)
        v[j] = W[(size_t)(kc * 64 + b * 8 + j) * HDIM + n];
    __align__(16) _Float16 h[8];
    #pragma unroll
    for (int i = 0; i < 8; i++) h[i] = (_Float16)v[i];
    size_t base = ((size_t)(n * 16 + kc)) * 128 + (size_t)((b ^ (n & 7)) * 16);
    *(uint4*)(dst + base) = *(const uint4*)h;
}

// ---------------------------------------------------------------------------
// Single-fp16 MFMA GEMM, single-barrier double-buffered (unchanged).
// ---------------------------------------------------------------------------
__global__ __launch_bounds__(256) void gemm_f16(
    const uchar* __restrict__ Ap, const uchar* __restrict__ Bp,
    float* __restrict__ C, int head_major)
{
    __shared__ __align__(16) uchar AB[65536];
    const int t = threadIdx.x, lane = t & 63, w = t >> 6;
    const int quad = lane >> 4, l15 = lane & 15, x7 = l15 & 7;
    const int m0 = blockIdx.y * 128, n0 = blockIdx.x * 128;
    const int wm = (w >> 1) * 64, wn = (w & 1) * 64;

    f32x4 acc[4][4];
    const f32x4 zero4 = {0.0f, 0.0f, 0.0f, 0.0f};
    #pragma unroll
    for (int mt = 0; mt < 4; mt++)
        #pragma unroll
        for (int nt = 0; nt < 4; nt++) acc[mt][nt] = zero4;

    #pragma unroll
    for (int i = 0; i < 4; i++) {
        int idx = i * 256 + t;
        int row = idx >> 3, blk = idx & 7;
        int ldso = (idx & ~63) * 16;
        async16(AB + ldso,         Ap + ((size_t)((m0 + row) * 16 + 0)) * 128 + blk * 16);
        async16(AB + 16384 + ldso, Bp + ((size_t)((n0 + row) * 16 + 0)) * 128 + blk * 16);
    }

    for (int kc = 0; kc < 16; kc++) {
        uchar* As = AB + (kc & 1) * 32768;
        uchar* Bs = As + 16384;
        __syncthreads();
        if (kc + 1 < 16) {
            uchar* An = AB + ((kc + 1) & 1) * 32768;
            #pragma unroll
            for (int i = 0; i < 4; i++) {
                int idx = i * 256 + t;
                int row = idx >> 3, blk = idx & 7;
                int ldso = (idx & ~63) * 16;
                async16(An + ldso,
                        Ap + ((size_t)((m0 + row) * 16 + kc + 1)) * 128 + blk * 16);
                async16(An + 16384 + ldso,
                        Bp + ((size_t)((n0 + row) * 16 + kc + 1)) * 128 + blk * 16);
            }
        }
        #pragma unroll
        for (int ks = 0; ks < 2; ks++) {
            const int phys = ((ks * 4 + quad) ^ x7) * 16;
            f16x8 ah[4];
            #pragma unroll
            for (int mt = 0; mt < 4; mt++)
                ah[mt] = *(const f16x8*)(As + (size_t)(wm + mt * 16 + l15) * 128 + phys);
            #pragma unroll
            for (int nt = 0; nt < 4; nt++) {
                f16x8 bh = *(const f16x8*)(Bs + (size_t)(wn + nt * 16 + l15) * 128 + phys);
                #pragma unroll
                for (int mt = 0; mt < 4; mt++)
                    acc[mt][nt] = mfma16h(ah[mt], bh, acc[mt][nt]);
            }
        }
    }

    #pragma unroll
    for (int mt = 0; mt < 4; mt++)
        #pragma unroll
        for (int nt = 0; nt < 4; nt++)
            #pragma unroll
            for (int r = 0; r < 4; r++) {
                int m = m0 + wm + mt * 16 + quad * 4 + r;
                int n = n0 + wn + nt * 16 + l15;
                float val = acc[mt][nt][r];
                if (head_major) {
                    int hh = n >> 6, d = n & 63;
                    C[((size_t)hh * S_LEN + m) * HD + d] = val;
                } else {
                    C[(size_t)m * HDIM + n] = val;
                }
            }
}

// ---------------------------------------------------------------------------
// RoPE + pack -> fp16 single, 128B rows (Q scaled 0.125*log2e)
// ---------------------------------------------------------------------------
__global__ __launch_bounds__(256) void rope_pack(const float* __restrict__ QKVf,
                                                 uchar* __restrict__ Qg,
                                                 uchar* __restrict__ Kg)
{
    int id = blockIdx.x * 256 + threadIdx.x;   // 2*16*4096*8
    int g  = id & 7;
    int s  = (id >> 3) & (S_LEN - 1);
    int hb = id >> 15;
    const float* src = QKVf + (size_t)hb * (S_LEN * HD) + (size_t)s * HD + g * 8;
    float v[8];
    *(float4*)&v[0] = *(const float4*)&src[0];
    *(float4*)&v[4] = *(const float4*)&src[4];

    const float L32 = 13.287712379549449f / 32.0f;
    float out[8];
    #pragma unroll
    for (int u = 0; u < 4; u++) {
        int de = g * 8 + 2 * u;
        float ae = (float)s * exp2f(-(float)(de & 31) * L32);
        float ao = (float)s * exp2f(-(float)((de + 1) & 31) * L32);
        float ce = __cosf(ae), se = __sinf(ae);
        float co = __cosf(ao), so = __sinf(ao);
        float xe = v[2 * u], xo = v[2 * u + 1];
        out[2 * u]     = xe * ce - xo * se;
        out[2 * u + 1] = xo * co + xe * so;
    }
    const bool isQ = hb < 16;
    const float scale = isQ ? 0.18033688011112042f : 1.0f;  // 0.125*log2e
    __align__(16) _Float16 h[8];
    #pragma unroll
    for (int i = 0; i < 8; i++) h[i] = (_Float16)(out[i] * scale);
    uchar* dst = (isQ ? Qg : Kg);
    size_t base = ((size_t)((hb & 15) * S_LEN + s)) * 128 + (size_t)((g ^ (s & 7)) * 16);
    *(uint4*)(dst + base) = *(const uint4*)h;
}

// ---------------------------------------------------------------------------
// V pack: fp32 head-major -> fp16 transposed 16KB tiles [head][32][64d][128k].
// Masked keys are ZEROED here (kills their o-contribution for free).
// ---------------------------------------------------------------------------
__global__ __launch_bounds__(256) void v_pack(const float* __restrict__ Vf,
                                              const int* __restrict__ M,
                                              uchar* __restrict__ Vg)
{
    int id = blockIdx.x * 256 + threadIdx.x;   // 16*32*16*64
    int d    = id & 63;
    int kg   = (id >> 6) & 15;
    int kc2  = (id >> 10) & 31;
    int head = id >> 15;
    __align__(16) _Float16 hv[8];
    #pragma unroll
    for (int j = 0; j < 8; j++) {
        int key = kc2 * 128 + kg * 8 + j;
        float x = Vf[(size_t)head * (S_LEN * HD) + (size_t)key * HD + d];
        hv[j] = (M[key] == 0) ? (_Float16)0.0f : (_Float16)x;
    }
    size_t base = ((size_t)(head * 32 + kc2)) * 16384 + (size_t)d * 256 +
                  (size_t)((kg ^ (d & 7)) * 16);
    *(uint4*)(Vg + base) = *(const uint4*)hv;
}

// ---------------------------------------------------------------------------
// attn8: barrier-free wave pipeline, 3 blocks/CU.
//  - V single-buffered (issued post-PV -> WAR-safe): 12KB/wave, 48KB arena.
//  - No softmax shift, no mask adds: p = 2^s (|s|<~12, fp16-safe; constant
//    factor cancels in o/l). Masked keys: V rows zeroed at pack (o), and
//    l computed by MFMA with per-key fp16 flags as the A operand (excludes
//    masked keys with zero VALU). RTZ-packed P; l sums the same truncated
//    P -> truncation bias cancels exactly in o/l.
//  - waitcnt schedule (batch/step = V4,K4,F1): top vmcnt(8), pre-PV vmcnt(4);
//    last step peeled with (4,0).
// ---------------------------------------------------------------------------
#define ISSUE_K(CC, KB)                                                        \
  {                                                                            \
    const uchar* ks_ = kgb + (size_t)(CC) * 16384;                             \
    async16((KB),        ks_ + l16);                                           \
    async16((KB) + 1024, ks_ + 1024 + l16);                                    \
    async16((KB) + 2048, ks_ + 2048 + l16);                                    \
    async16((KB) + 3072, ks_ + 3072 + l16);                                    \
  }
#define ISSUE_V(CC)                                                            \
  {                                                                            \
    const uchar* vs_ = vgb + (size_t)(CC) * 16384;                             \
    async16(VB,        vs_ + voff);                                            \
    async16(VB + 1024, vs_ + 4096 + voff);                                     \
    async16(VB + 2048, vs_ + 8192 + voff);                                     \
    async16(VB + 3072, vs_ + 12288 + voff);                                    \
  }

#define ATTN_STEP(CC, KB, TOPC, MIDC, FLG)                                     \
  {                                                                            \
    asm volatile("s_waitcnt vmcnt(" TOPC ")" ::: "memory");                    \
    f32x4 s0[4], s1[4];                                                        \
    _Pragma("unroll")                                                          \
    for (int qt = 0; qt < 4; qt++) { s0[qt] = zero4; s1[qt] = zero4; }         \
    _Pragma("unroll")                                                          \
    for (int ks = 0; ks < 2; ks++) {                                           \
      const int phys_ = ((ks * 4 + quad) ^ x7) * 16;                           \
      f16x8 kf0 = *(const f16x8*)((KB) + (size_t)l15 * 128 + phys_);           \
      f16x8 kf1 = *(const f16x8*)((KB) + (size_t)(16 + l15) * 128 + phys_);    \
      _Pragma("unroll")                                                        \
      for (int qt = 0; qt < 4; qt++) {                                         \
        s0[qt] = mfma16h(kf0, qf[qt][ks], s0[qt]);                             \
        s1[qt] = mfma16h(kf1, qf[qt][ks], s1[qt]);                             \
      }                                                                        \
    }                                                                          \
    uchar* Pw_ = (KB);                                                         \
    _Pragma("unroll")                                                          \
    for (int qt = 0; qt < 4; qt++) {                                           \
      h16x2 c01 = __builtin_amdgcn_cvt_pkrtz(exp2f(s0[qt][0]), exp2f(s0[qt][1])); \
      h16x2 c23 = __builtin_amdgcn_cvt_pkrtz(exp2f(s0[qt][2]), exp2f(s0[qt][3])); \
      h16x2 c45 = __builtin_amdgcn_cvt_pkrtz(exp2f(s1[qt][0]), exp2f(s1[qt][1])); \
      h16x2 c67 = __builtin_amdgcn_cvt_pkrtz(exp2f(s1[qt][2]), exp2f(s1[qt][3])); \
      uint2 a0 = make_uint2(__builtin_bit_cast(u32, c01),                      \
                            __builtin_bit_cast(u32, c23));                     \
      uint2 a1 = make_uint2(__builtin_bit_cast(u32, c45),                      \
                            __builtin_bit_cast(u32, c67));                     \
      uchar* prow_ = Pw_ + (size_t)(qt * 16 + l15) * 64 + (quad & 1) * 8;      \
      *(uint2*)(prow_ + ((((quad >> 1)) ^ psw) * 16))     = a0;                \
      *(uint2*)(prow_ + (((2 + (quad >> 1)) ^ psw) * 16)) = a1;                \
    }                                                                          \
    asm volatile("s_waitcnt vmcnt(" MIDC ")" ::: "memory");                    \
    {                                                                          \
      f16x8 pb[4];                                                             \
      _Pragma("unroll")                                                        \
      for (int qt = 0; qt < 4; qt++)                                           \
        pb[qt] = *(const f16x8*)(Pw_ + (size_t)(qt * 16 + l15) * 64 +          \
                                 ((quad ^ psw) * 16));                         \
      _Pragma("unroll")                                                        \
      for (int dt = 0; dt < 4; dt++) {                                         \
        f16x8 va = *(const f16x8*)(VB + (size_t)(dt * 16 + l15) * 64 + vrd);   \
        _Pragma("unroll")                                                      \
        for (int qt = 0; qt < 4; qt++)                                         \
          o[dt][qt] = mfma16h(va, pb[qt], o[dt][qt]);                          \
      }                                                                        \
      _Pragma("unroll")                                                        \
      for (int qt = 0; qt < 4; qt++)                                           \
        lacc[qt] = mfma16h((FLG), pb[qt], lacc[qt]);                           \
    }                                                                          \
    asm volatile("s_waitcnt lgkmcnt(0)" ::: "memory");                         \
    if ((CC) + 1 < 32) ISSUE_V((CC) + 1);                                      \
    if ((CC) + 2 < 32) {                                                       \
      ISSUE_K((CC) + 2, KB);                                                   \
      (FLG) = *(const f16x8*)(fmw + (size_t)((CC) + 2) * 256);                 \
    }                                                                          \
  }

__global__ __launch_bounds__(256, 3) void attn8(
    const uchar* __restrict__ Qg, const uchar* __restrict__ Kg,
    const uchar* __restrict__ Vg, const uchar* __restrict__ fm16,
    uchar* __restrict__ CTXp)
{
    __shared__ __align__(16) uchar arena[49152];   // 4 waves x [K0|K1|V] 4KB
    __shared__ float Lsh[4][64];
    __shared__ float Lfin[64];
    float* Os = (float*)arena;                     // merge overlay (after loop)

    const int t    = threadIdx.x;
    const int lane = t & 63;
    const int w    = t >> 6;
    const int quad = lane >> 4;
    const int l15  = lane & 15;
    const int x7   = l15 & 7;
    const int hh   = blockIdx.y;
    const int m0   = blockIdx.x * 64;

    const uchar* qgb = Qg + (size_t)hh * (S_LEN * 128);
    const uchar* kgb = Kg + (size_t)hh * (S_LEN * 128) + (size_t)w * 4096;
    const uchar* vgb = Vg + (size_t)hh * 32 * 16384;
    const uchar* fmw = fm16 + w * 64 + quad * 16;

    uchar* WB = arena + w * 12288;
    uchar* K0 = WB;
    uchar* K1 = WB + 4096;
    uchar* VB = WB + 8192;

    const int l16 = lane * 16;
    const int vphys = ((w * 4 + ((lane & 3) ^ ((lane >> 2) & 3))) ^ ((lane >> 2) & 7));
    const int voff  = (lane >> 2) * 256 + vphys * 16;
    const int vrd   = (quad ^ (l15 & 3)) * 16;
    const int psw   = (l15 >> 1) & 3;

    // ---- Q fragments -> registers, once ----
    f16x8 qf[4][2];
    #pragma unroll
    for (int qt = 0; qt < 4; qt++)
        #pragma unroll
        for (int ks = 0; ks < 2; ks++)
            qf[qt][ks] = *(const f16x8*)(qgb + (size_t)(m0 + qt * 16 + l15) * 128 +
                                         (size_t)(((ks * 4 + quad) ^ x7) * 16));

    f32x4 o[4][4], lacc[4];
    const f32x4 zero4 = {0.0f, 0.0f, 0.0f, 0.0f};
    #pragma unroll
    for (int dt = 0; dt < 4; dt++)
        #pragma unroll
        for (int qt = 0; qt < 4; qt++) o[dt][qt] = zero4;
    #pragma unroll
    for (int qt = 0; qt < 4; qt++) lacc[qt] = zero4;

    // ---- prologue ----
    ISSUE_K(0, K0);
    ISSUE_V(0);
    f16x8 flagA = *(const f16x8*)(fmw);
    f16x8 flagB = *(const f16x8*)(fmw + 256);
    ISSUE_K(1, K1);

    for (int c = 0; c < 30; c += 2) {
        ATTN_STEP(c,     K0, "8", "4", flagA);
        ATTN_STEP(c + 1, K1, "8", "4", flagB);
    }
    ATTN_STEP(30, K0, "8", "4", flagA);
    ATTN_STEP(31, K1, "4", "0", flagB);

    // ---- l finalize: lane holds full slice sum (key-dim summed by MFMA) ----
    __syncthreads();                 // all waves done; arena reusable
    if (quad == 0) {
        #pragma unroll
        for (int qt = 0; qt < 4; qt++)
            Lsh[w][qt * 16 + l15] = lacc[qt][0];
    }
    __syncthreads();
    if (t < 64)
        Lfin[t] = Lsh[0][t] + Lsh[1][t] + Lsh[2][t] + Lsh[3][t];
    __syncthreads();

    // ---- o merge: plain sum across waves ----
    for (int wv = 0; wv < 4; wv++) {
        if (w == wv) {
            #pragma unroll
            for (int dt = 0; dt < 4; dt++)
                #pragma unroll
                for (int qt = 0; qt < 4; qt++)
                    #pragma unroll
                    for (int r = 0; r < 4; r++) {
                        int q = qt * 16 + l15;
                        int d = dt * 16 + quad * 4 + r;
                        float val = o[dt][qt][r];
                        if (wv == 0) Os[q * 68 + d] = val;
                        else         Os[q * 68 + d] += val;
                    }
        }
        __syncthreads();
    }

    // ---- epilogue: ctx packed fp16, kc = head (feeds Wo GEMM) ----
    #pragma unroll
    for (int i = 0; i < 4; i++) {
        int idx = t + 256 * i;
        int q   = idx >> 4;
        int c4  = (idx & 15) * 4;
        float inv = 1.0f / Lfin[q];
        float4 v = *(const float4*)&Os[q * 68 + c4];
        int m = m0 + q;
        __align__(8) _Float16 h[4];
        h[0] = (_Float16)(v.x * inv);
        h[1] = (_Float16)(v.y * inv);
        h[2] = (_Float16)(v.z * inv);
        h[3] = (_Float16)(v.w * inv);
        size_t base = ((size_t)(m * 16 + hh)) * 128 +
                      (size_t)((((c4 >> 3) ^ (m & 7))) * 16) + (c4 & 7) * 2;
        *(ushort4*)(CTXp + base) = *(const ushort4*)h;
    }
}

// ---------------------------------------------------------------------------
extern "C" void kernel_launch(void* const* d_in, const int* in_sizes, int n_in,
                              void* d_out, int out_size, void* d_ws, size_t ws_size,
                              hipStream_t stream)
{
    const float* x   = (const float*)d_in[0];
    const float* Wq  = (const float*)d_in[1];
    const float* Wk  = (const float*)d_in[2];
    const float* Wv  = (const float*)d_in[3];
    const float* Wo  = (const float*)d_in[4];
    const int* amask = (const int*)d_in[5];
    float* out = (float*)d_out;
    float* ws  = (float*)d_ws;

    // byte-offset workspace map:
    //   QKVf  fp32 [48][4096][64]   bytes [0, 50331648)
    //   Xp    fp16 packed x (8.4MB) bytes [50331648, 58720256)  later = Qg
    //   Wt4   fp16 packed W^T x4    bytes [58720256, 67108864)  (2MB each)
    //   Vg    fp16 V tiles (8.4MB)  bytes [67108864, 75497472)
    //   Fm16  fp16 flags (8KB)      bytes [75497472, 75505664)
    //   Kg    = bytes [33554432, 41943040)   (over Vf, dead after v_pack)
    //   CTXp  = bytes [0, 8388608)           (over Qf, dead after rope)
    float* QKVf = ws;
    uchar* Xp   = (uchar*)ws + 50331648;
    uchar* Wt4  = (uchar*)ws + 58720256;
    uchar* Vg   = (uchar*)ws + 67108864;
    _Float16* Fm16 = (_Float16*)((uchar*)ws + 75497472);
    uchar* Qg   = Xp;
    uchar* Kg   = (uchar*)ws + 33554432;
    uchar* CTXp = (uchar*)ws;

    dim3 blk(256);

    pack_x<<<2048, blk, 0, stream>>>(x, Xp, amask, Fm16);
    pack_w4<<<2048, blk, 0, stream>>>(Wq, Wk, Wv, Wo, Wt4);

    // fused QKV projection: N = 3072, head-major out (heads 0..47)
    gemm_f16<<<dim3(24, 32), blk, 0, stream>>>(Xp, Wt4, QKVf, 1);

    // V pack BEFORE rope (Kg aliases Vf region); masked V rows zeroed here
    v_pack<<<2048, blk, 0, stream>>>(QKVf + 8388608, amask, Vg);
    rope_pack<<<4096, blk, 0, stream>>>(QKVf, Qg, Kg);

    attn8<<<dim3(S_LEN / 64, NHEADS), blk, 0, stream>>>(Qg, Kg, Vg,
                                                        (const uchar*)Fm16, CTXp);

    // output projection: N = 1024, row-major out (Wo at Wt4 + 3*2MB)
    gemm_f16<<<dim3(8, 32), blk, 0, stream>>>(CTXp, Wt4 + 6291456, out, 0);
}

// Round 12
// 264.325 us; speedup vs baseline: 1.3711x; 1.3711x over previous
//
#include <hip/hip_runtime.h>
#include <cstdint>
#include <cstddef>

// Problem constants (B=1, S=4096, H=1024, 16 heads x 64)
#define S_LEN 4096
#define NHEADS 16
#define HD 64
#define HDIM 1024

typedef _Float16 f16x8 __attribute__((ext_vector_type(8)));
typedef _Float16 f16x4 __attribute__((ext_vector_type(4)));
typedef __fp16 h16x2 __attribute__((ext_vector_type(2)));   // cvt_pkrtz native
typedef float f32x4 __attribute__((ext_vector_type(4)));
typedef unsigned char uchar;
typedef unsigned int u32;

__device__ __forceinline__ f32x4 mfma16h(f16x8 a, f16x8 b, f32x4 c) {
    return __builtin_amdgcn_mfma_f32_16x16x32_f16(a, b, c, 0, 0, 0);
}
// async global->LDS, 16B/lane; lds must be wave-uniform base (HW adds lane*16)
__device__ __forceinline__ void async16(void* lds, const void* g) {
    __builtin_amdgcn_global_load_lds(
        (const __attribute__((address_space(1))) u32*)g,
        (__attribute__((address_space(3))) u32*)lds, 16, 0, 0);
}

// ---------------------------------------------------------------------------
// Packed fp16 format: per 64-elem logical row, a 128B record of 8 x 16B
// blocks XOR-swizzled: element e of row r lives at ((e>>3)^(r&7))*16+(e&7)*2.
// Byte layout == LDS image -> staging is straight 16B async copies.
// ---------------------------------------------------------------------------

// x [4096][1024] fp32 -> Xp [m][kc=16][128B]; also emits fp16 key flags {0,1}
__global__ __launch_bounds__(256) void pack_x(const float* __restrict__ X,
                                              uchar* __restrict__ P,
                                              const int* __restrict__ M,
                                              _Float16* __restrict__ FM16)
{
    int id = blockIdx.x * 256 + threadIdx.x;       // 4096*128
    int m = id >> 7, g = id & 127;
    int kc = g >> 3, b = g & 7;
    float v[8];
    *(float4*)&v[0] = *(const float4*)&X[(size_t)m * HDIM + kc * 64 + b * 8];
    *(float4*)&v[4] = *(const float4*)&X[(size_t)m * HDIM + kc * 64 + b * 8 + 4];
    __align__(16) _Float16 h[8];
    #pragma unroll
    for (int i = 0; i < 8; i++) h[i] = (_Float16)v[i];
    size_t base = ((size_t)(m * 16 + kc)) * 128 + (size_t)((b ^ (m & 7)) * 16);
    *(uint4*)(P + base) = *(const uint4*)h;
    if (id < S_LEN) FM16[id] = (_Float16)((M[id] == 0) ? 0.0f : 1.0f);
}

// All 4 weight matrices [1024 k][1024 n] fp32 -> fp16 B^T rows [n][kc=16][128B]
__global__ __launch_bounds__(256) void pack_w4(
    const float* __restrict__ W0, const float* __restrict__ W1,
    const float* __restrict__ W2, const float* __restrict__ W3,
    uchar* __restrict__ P)
{
    int id = blockIdx.x * 256 + threadIdx.x;       // 4*128*1024
    int wsel = id >> 17;
    int lid  = id & 131071;
    int g = lid >> 10, n = lid & 1023;
    int kc = g >> 3, b = g & 7;
    const float* W = (wsel == 0) ? W0 : (wsel == 1) ? W1 : (wsel == 2) ? W2 : W3;
    uchar* dst = P + (size_t)wsel * 2097152;
    float v[8];
    #pragma unroll
    for (int j = 0; j < 8; j++)
        v[j] = W[(size_t)(kc * 64 + b * 8 + j) * HDIM + n];
    __align__(16) _Float16 h[8];
    #pragma unroll
    for (int i = 0; i < 8; i++) h[i] = (_Float16)v[i];
    size_t base = ((size_t)(n * 16 + kc)) * 128 + (size_t)((b ^ (n & 7)) * 16);
    *(uint4*)(dst + base) = *(const uint4*)h;
}

// ---------------------------------------------------------------------------
// Single-fp16 MFMA GEMM, single-barrier double-buffered (unchanged).
// ---------------------------------------------------------------------------
__global__ __launch_bounds__(256) void gemm_f16(
    const uchar* __restrict__ Ap, const uchar* __restrict__ Bp,
    float* __restrict__ C, int head_major)
{
    __shared__ __align__(16) uchar AB[65536];
    const int t = threadIdx.x, lane = t & 63, w = t >> 6;
    const int quad = lane >> 4, l15 = lane & 15, x7 = l15 & 7;
    const int m0 = blockIdx.y * 128, n0 = blockIdx.x * 128;
    const int wm = (w >> 1) * 64, wn = (w & 1) * 64;

    f32x4 acc[4][4];
    const f32x4 zero4 = {0.0f, 0.0f, 0.0f, 0.0f};
    #pragma unroll
    for (int mt = 0; mt < 4; mt++)
        #pragma unroll
        for (int nt = 0; nt < 4; nt++) acc[mt][nt] = zero4;

    #pragma unroll
    for (int i = 0; i < 4; i++) {
        int idx = i * 256 + t;
        int row = idx >> 3, blk = idx & 7;
        int ldso = (idx & ~63) * 16;
        async16(AB + ldso,         Ap + ((size_t)((m0 + row) * 16 + 0)) * 128 + blk * 16);
        async16(AB + 16384 + ldso, Bp + ((size_t)((n0 + row) * 16 + 0)) * 128 + blk * 16);
    }

    for (int kc = 0; kc < 16; kc++) {
        uchar* As = AB + (kc & 1) * 32768;
        uchar* Bs = As + 16384;
        __syncthreads();
        if (kc + 1 < 16) {
            uchar* An = AB + ((kc + 1) & 1) * 32768;
            #pragma unroll
            for (int i = 0; i < 4; i++) {
                int idx = i * 256 + t;
                int row = idx >> 3, blk = idx & 7;
                int ldso = (idx & ~63) * 16;
                async16(An + ldso,
                        Ap + ((size_t)((m0 + row) * 16 + kc + 1)) * 128 + blk * 16);
                async16(An + 16384 + ldso,
                        Bp + ((size_t)((n0 + row) * 16 + kc + 1)) * 128 + blk * 16);
            }
        }
        #pragma unroll
        for (int ks = 0; ks < 2; ks++) {
            const int phys = ((ks * 4 + quad) ^ x7) * 16;
            f16x8 ah[4];
            #pragma unroll
            for (int mt = 0; mt < 4; mt++)
                ah[mt] = *(const f16x8*)(As + (size_t)(wm + mt * 16 + l15) * 128 + phys);
            #pragma unroll
            for (int nt = 0; nt < 4; nt++) {
                f16x8 bh = *(const f16x8*)(Bs + (size_t)(wn + nt * 16 + l15) * 128 + phys);
                #pragma unroll
                for (int mt = 0; mt < 4; mt++)
                    acc[mt][nt] = mfma16h(ah[mt], bh, acc[mt][nt]);
            }
        }
    }

    #pragma unroll
    for (int mt = 0; mt < 4; mt++)
        #pragma unroll
        for (int nt = 0; nt < 4; nt++)
            #pragma unroll
            for (int r = 0; r < 4; r++) {
                int m = m0 + wm + mt * 16 + quad * 4 + r;
                int n = n0 + wn + nt * 16 + l15;
                float val = acc[mt][nt][r];
                if (head_major) {
                    int hh = n >> 6, d = n & 63;
                    C[((size_t)hh * S_LEN + m) * HD + d] = val;
                } else {
                    C[(size_t)m * HDIM + n] = val;
                }
            }
}

// ---------------------------------------------------------------------------
// RoPE + pack -> fp16 single, 128B rows (Q scaled 0.125*log2e)
// ---------------------------------------------------------------------------
__global__ __launch_bounds__(256) void rope_pack(const float* __restrict__ QKVf,
                                                 uchar* __restrict__ Qg,
                                                 uchar* __restrict__ Kg)
{
    int id = blockIdx.x * 256 + threadIdx.x;   // 2*16*4096*8
    int g  = id & 7;
    int s  = (id >> 3) & (S_LEN - 1);
    int hb = id >> 15;
    const float* src = QKVf + (size_t)hb * (S_LEN * HD) + (size_t)s * HD + g * 8;
    float v[8];
    *(float4*)&v[0] = *(const float4*)&src[0];
    *(float4*)&v[4] = *(const float4*)&src[4];

    const float L32 = 13.287712379549449f / 32.0f;
    float out[8];
    #pragma unroll
    for (int u = 0; u < 4; u++) {
        int de = g * 8 + 2 * u;
        float ae = (float)s * exp2f(-(float)(de & 31) * L32);
        float ao = (float)s * exp2f(-(float)((de + 1) & 31) * L32);
        float ce = __cosf(ae), se = __sinf(ae);
        float co = __cosf(ao), so = __sinf(ao);
        float xe = v[2 * u], xo = v[2 * u + 1];
        out[2 * u]     = xe * ce - xo * se;
        out[2 * u + 1] = xo * co + xe * so;
    }
    const bool isQ = hb < 16;
    const float scale = isQ ? 0.18033688011112042f : 1.0f;  // 0.125*log2e
    __align__(16) _Float16 h[8];
    #pragma unroll
    for (int i = 0; i < 8; i++) h[i] = (_Float16)(out[i] * scale);
    uchar* dst = (isQ ? Qg : Kg);
    size_t base = ((size_t)((hb & 15) * S_LEN + s)) * 128 + (size_t)((g ^ (s & 7)) * 16);
    *(uint4*)(dst + base) = *(const uint4*)h;
}

// ---------------------------------------------------------------------------
// V pack: fp32 head-major -> fp16 transposed 16KB tiles [head][32][64d][128k].
// Masked keys are ZEROED here (kills their o-contribution for free).
// ---------------------------------------------------------------------------
__global__ __launch_bounds__(256) void v_pack(const float* __restrict__ Vf,
                                              const int* __restrict__ M,
                                              uchar* __restrict__ Vg)
{
    int id = blockIdx.x * 256 + threadIdx.x;   // 16*32*16*64
    int d    = id & 63;
    int kg   = (id >> 6) & 15;
    int kc2  = (id >> 10) & 31;
    int head = id >> 15;
    __align__(16) _Float16 hv[8];
    #pragma unroll
    for (int j = 0; j < 8; j++) {
        int key = kc2 * 128 + kg * 8 + j;
        float x = Vf[(size_t)head * (S_LEN * HD) + (size_t)key * HD + d];
        hv[j] = (M[key] == 0) ? (_Float16)0.0f : (_Float16)x;
    }
    size_t base = ((size_t)(head * 32 + kc2)) * 16384 + (size_t)d * 256 +
                  (size_t)((kg ^ (d & 7)) * 16);
    *(uint4*)(Vg + base) = *(const uint4*)hv;
}

// ---------------------------------------------------------------------------
// attn8b: barrier-free wave pipeline. launch_bounds(256,2) — R10's (256,3)
// forced ~170 regs/wave (unified VGPR+AGPR) vs ~200 live -> scratch spills
// (WRITE_SIZE 8->285MB). At (256,2) everything stays in registers.
//  - V single-buffered (issued post-PV -> WAR-safe): 12KB/wave, 48KB arena.
//  - p = 2^s, no shift/mask adds; masked keys: V rows zeroed at pack, l via
//    MFMA with fp16 flag fragment as A operand. RTZ-packed P; l sums the
//    same truncated P -> truncation bias cancels in o/l.
//  - waitcnt: top vmcnt(8), pre-PV vmcnt(4); last step peeled (4,0).
// ---------------------------------------------------------------------------
#define ISSUE_K(CC, KB)                                                        \
  {                                                                            \
    const uchar* ks_ = kgb + (size_t)(CC) * 16384;                             \
    async16((KB),        ks_ + l16);                                           \
    async16((KB) + 1024, ks_ + 1024 + l16);                                    \
    async16((KB) + 2048, ks_ + 2048 + l16);                                    \
    async16((KB) + 3072, ks_ + 3072 + l16);                                    \
  }
#define ISSUE_V(CC)                                                            \
  {                                                                            \
    const uchar* vs_ = vgb + (size_t)(CC) * 16384;                             \
    async16(VB,        vs_ + voff);                                            \
    async16(VB + 1024, vs_ + 4096 + voff);                                     \
    async16(VB + 2048, vs_ + 8192 + voff);                                     \
    async16(VB + 3072, vs_ + 12288 + voff);                                    \
  }

#define ATTN_STEP(CC, KB, TOPC, MIDC, FLG)                                     \
  {                                                                            \
    asm volatile("s_waitcnt vmcnt(" TOPC ")" ::: "memory");                    \
    f32x4 s0[4], s1[4];                                                        \
    _Pragma("unroll")                                                          \
    for (int qt = 0; qt < 4; qt++) { s0[qt] = zero4; s1[qt] = zero4; }         \
    _Pragma("unroll")                                                          \
    for (int ks = 0; ks < 2; ks++) {                                           \
      const int phys_ = ((ks * 4 + quad) ^ x7) * 16;                           \
      f16x8 kf0 = *(const f16x8*)((KB) + (size_t)l15 * 128 + phys_);           \
      f16x8 kf1 = *(const f16x8*)((KB) + (size_t)(16 + l15) * 128 + phys_);    \
      _Pragma("unroll")                                                        \
      for (int qt = 0; qt < 4; qt++) {                                         \
        s0[qt] = mfma16h(kf0, qf[qt][ks], s0[qt]);                             \
        s1[qt] = mfma16h(kf1, qf[qt][ks], s1[qt]);                             \
      }                                                                        \
    }                                                                          \
    uchar* Pw_ = (KB);                                                         \
    _Pragma("unroll")                                                          \
    for (int qt = 0; qt < 4; qt++) {                                           \
      h16x2 c01 = __builtin_amdgcn_cvt_pkrtz(exp2f(s0[qt][0]), exp2f(s0[qt][1])); \
      h16x2 c23 = __builtin_amdgcn_cvt_pkrtz(exp2f(s0[qt][2]), exp2f(s0[qt][3])); \
      h16x2 c45 = __builtin_amdgcn_cvt_pkrtz(exp2f(s1[qt][0]), exp2f(s1[qt][1])); \
      h16x2 c67 = __builtin_amdgcn_cvt_pkrtz(exp2f(s1[qt][2]), exp2f(s1[qt][3])); \
      uint2 a0 = make_uint2(__builtin_bit_cast(u32, c01),                      \
                            __builtin_bit_cast(u32, c23));                     \
      uint2 a1 = make_uint2(__builtin_bit_cast(u32, c45),                      \
                            __builtin_bit_cast(u32, c67));                     \
      uchar* prow_ = Pw_ + (size_t)(qt * 16 + l15) * 64 + (quad & 1) * 8;      \
      *(uint2*)(prow_ + ((((quad >> 1)) ^ psw) * 16))     = a0;                \
      *(uint2*)(prow_ + (((2 + (quad >> 1)) ^ psw) * 16)) = a1;                \
    }                                                                          \
    asm volatile("s_waitcnt vmcnt(" MIDC ")" ::: "memory");                    \
    {                                                                          \
      f16x8 pb[4];                                                             \
      _Pragma("unroll")                                                        \
      for (int qt = 0; qt < 4; qt++)                                           \
        pb[qt] = *(const f16x8*)(Pw_ + (size_t)(qt * 16 + l15) * 64 +          \
                                 ((quad ^ psw) * 16));                         \
      _Pragma("unroll")                                                        \
      for (int dt = 0; dt < 4; dt++) {                                         \
        f16x8 va = *(const f16x8*)(VB + (size_t)(dt * 16 + l15) * 64 + vrd);   \
        _Pragma("unroll")                                                      \
        for (int qt = 0; qt < 4; qt++)                                         \
          o[dt][qt] = mfma16h(va, pb[qt], o[dt][qt]);                          \
      }                                                                        \
      _Pragma("unroll")                                                        \
      for (int qt = 0; qt < 4; qt++)                                           \
        lacc[qt] = mfma16h((FLG), pb[qt], lacc[qt]);                           \
    }                                                                          \
    asm volatile("s_waitcnt lgkmcnt(0)" ::: "memory");                         \
    if ((CC) + 1 < 32) ISSUE_V((CC) + 1);                                      \
    if ((CC) + 2 < 32) {                                                       \
      ISSUE_K((CC) + 2, KB);                                                   \
      (FLG) = *(const f16x8*)(fmw + (size_t)((CC) + 2) * 256);                 \
    }                                                                          \
  }

__global__ __launch_bounds__(256, 2) void attn8b(
    const uchar* __restrict__ Qg, const uchar* __restrict__ Kg,
    const uchar* __restrict__ Vg, const uchar* __restrict__ fm16,
    uchar* __restrict__ CTXp)
{
    __shared__ __align__(16) uchar arena[49152];   // 4 waves x [K0|K1|V] 4KB
    __shared__ float Lsh[4][64];
    __shared__ float Lfin[64];
    float* Os = (float*)arena;                     // merge overlay (after loop)

    const int t    = threadIdx.x;
    const int lane = t & 63;
    const int w    = t >> 6;
    const int quad = lane >> 4;
    const int l15  = lane & 15;
    const int x7   = l15 & 7;
    const int hh   = blockIdx.y;
    const int m0   = blockIdx.x * 64;

    const uchar* qgb = Qg + (size_t)hh * (S_LEN * 128);
    const uchar* kgb = Kg + (size_t)hh * (S_LEN * 128) + (size_t)w * 4096;
    const uchar* vgb = Vg + (size_t)hh * 32 * 16384;
    const uchar* fmw = fm16 + w * 64 + quad * 16;

    uchar* WB = arena + w * 12288;
    uchar* K0 = WB;
    uchar* K1 = WB + 4096;
    uchar* VB = WB + 8192;

    const int l16 = lane * 16;
    const int vphys = ((w * 4 + ((lane & 3) ^ ((lane >> 2) & 3))) ^ ((lane >> 2) & 7));
    const int voff  = (lane >> 2) * 256 + vphys * 16;
    const int vrd   = (quad ^ (l15 & 3)) * 16;
    const int psw   = (l15 >> 1) & 3;

    // ---- Q fragments -> registers, once ----
    f16x8 qf[4][2];
    #pragma unroll
    for (int qt = 0; qt < 4; qt++)
        #pragma unroll
        for (int ks = 0; ks < 2; ks++)
            qf[qt][ks] = *(const f16x8*)(qgb + (size_t)(m0 + qt * 16 + l15) * 128 +
                                         (size_t)(((ks * 4 + quad) ^ x7) * 16));

    f32x4 o[4][4], lacc[4];
    const f32x4 zero4 = {0.0f, 0.0f, 0.0f, 0.0f};
    #pragma unroll
    for (int dt = 0; dt < 4; dt++)
        #pragma unroll
        for (int qt = 0; qt < 4; qt++) o[dt][qt] = zero4;
    #pragma unroll
    for (int qt = 0; qt < 4; qt++) lacc[qt] = zero4;

    // ---- prologue ----
    ISSUE_K(0, K0);
    ISSUE_V(0);
    f16x8 flagA = *(const f16x8*)(fmw);
    f16x8 flagB = *(const f16x8*)(fmw + 256);
    ISSUE_K(1, K1);

    for (int c = 0; c < 30; c += 2) {
        ATTN_STEP(c,     K0, "8", "4", flagA);
        ATTN_STEP(c + 1, K1, "8", "4", flagB);
    }
    ATTN_STEP(30, K0, "8", "4", flagA);
    ATTN_STEP(31, K1, "4", "0", flagB);

    // ---- l finalize: lane holds full slice sum (key-dim summed by MFMA) ----
    __syncthreads();                 // all waves done; arena reusable
    if (quad == 0) {
        #pragma unroll
        for (int qt = 0; qt < 4; qt++)
            Lsh[w][qt * 16 + l15] = lacc[qt][0];
    }
    __syncthreads();
    if (t < 64)
        Lfin[t] = Lsh[0][t] + Lsh[1][t] + Lsh[2][t] + Lsh[3][t];
    __syncthreads();

    // ---- o merge: plain sum across waves ----
    for (int wv = 0; wv < 4; wv++) {
        if (w == wv) {
            #pragma unroll
            for (int dt = 0; dt < 4; dt++)
                #pragma unroll
                for (int qt = 0; qt < 4; qt++)
                    #pragma unroll
                    for (int r = 0; r < 4; r++) {
                        int q = qt * 16 + l15;
                        int d = dt * 16 + quad * 4 + r;
                        float val = o[dt][qt][r];
                        if (wv == 0) Os[q * 68 + d] = val;
                        else         Os[q * 68 + d] += val;
                    }
        }
        __syncthreads();
    }

    // ---- epilogue: ctx packed fp16, kc = head (feeds Wo GEMM) ----
    #pragma unroll
    for (int i = 0; i < 4; i++) {
        int idx = t + 256 * i;
        int q   = idx >> 4;
        int c4  = (idx & 15) * 4;
        float inv = 1.0f / Lfin[q];
        float4 v = *(const float4*)&Os[q * 68 + c4];
        int m = m0 + q;
        __align__(8) _Float16 h[4];
        h[0] = (_Float16)(v.x * inv);
        h[1] = (_Float16)(v.y * inv);
        h[2] = (_Float16)(v.z * inv);
        h[3] = (_Float16)(v.w * inv);
        size_t base = ((size_t)(m * 16 + hh)) * 128 +
                      (size_t)((((c4 >> 3) ^ (m & 7))) * 16) + (c4 & 7) * 2;
        *(ushort4*)(CTXp + base) = *(const ushort4*)h;
    }
}

// ---------------------------------------------------------------------------
extern "C" void kernel_launch(void* const* d_in, const int* in_sizes, int n_in,
                              void* d_out, int out_size, void* d_ws, size_t ws_size,
                              hipStream_t stream)
{
    const float* x   = (const float*)d_in[0];
    const float* Wq  = (const float*)d_in[1];
    const float* Wk  = (const float*)d_in[2];
    const float* Wv  = (const float*)d_in[3];
    const float* Wo  = (const float*)d_in[4];
    const int* amask = (const int*)d_in[5];
    float* out = (float*)d_out;
    float* ws  = (float*)d_ws;

    // byte-offset workspace map:
    //   QKVf  fp32 [48][4096][64]   bytes [0, 50331648)
    //   Xp    fp16 packed x (8.4MB) bytes [50331648, 58720256)  later = Qg
    //   Wt4   fp16 packed W^T x4    bytes [58720256, 67108864)  (2MB each)
    //   Vg    fp16 V tiles (8.4MB)  bytes [67108864, 75497472)
    //   Fm16  fp16 flags (8KB)      bytes [75497472, 75505664)
    //   Kg    = bytes [33554432, 41943040)   (over Vf, dead after v_pack)
    //   CTXp  = bytes [0, 8388608)           (over Qf, dead after rope)
    float* QKVf = ws;
    uchar* Xp   = (uchar*)ws + 50331648;
    uchar* Wt4  = (uchar*)ws + 58720256;
    uchar* Vg   = (uchar*)ws + 67108864;
    _Float16* Fm16 = (_Float16*)((uchar*)ws + 75497472);
    uchar* Qg   = Xp;
    uchar* Kg   = (uchar*)ws + 33554432;
    uchar* CTXp = (uchar*)ws;

    dim3 blk(256);

    pack_x<<<2048, blk, 0, stream>>>(x, Xp, amask, Fm16);
    pack_w4<<<2048, blk, 0, stream>>>(Wq, Wk, Wv, Wo, Wt4);

    // fused QKV projection: N = 3072, head-major out (heads 0..47)
    gemm_f16<<<dim3(24, 32), blk, 0, stream>>>(Xp, Wt4, QKVf, 1);

    // V pack BEFORE rope (Kg aliases Vf region); masked V rows zeroed here
    v_pack<<<2048, blk, 0, stream>>>(QKVf + 8388608, amask, Vg);
    rope_pack<<<4096, blk, 0, stream>>>(QKVf, Qg, Kg);

    attn8b<<<dim3(S_LEN / 64, NHEADS), blk, 0, stream>>>(Qg, Kg, Vg,
                                                         (const uchar*)Fm16, CTXp);

    // output projection: N = 1024, row-major out (Wo at Wt4 + 3*2MB)
    gemm_f16<<<dim3(8, 32), blk, 0, stream>>>(CTXp, Wt4 + 6291456, out, 0);
}

// Round 13
// 252.377 us; speedup vs baseline: 1.4360x; 1.0473x over previous
//
#include <hip/hip_runtime.h>
#include <cstdint>
#include <cstddef>

// Problem constants (B=1, S=4096, H=1024, 16 heads x 64)
#define S_LEN 4096
#define NHEADS 16
#define HD 64
#define HDIM 1024

typedef _Float16 f16x8 __attribute__((ext_vector_type(8)));
typedef _Float16 f16x4 __attribute__((ext_vector_type(4)));
typedef __fp16 h16x2 __attribute__((ext_vector_type(2)));   // cvt_pkrtz native
typedef float f32x4 __attribute__((ext_vector_type(4)));
typedef unsigned char uchar;
typedef unsigned int u32;

__device__ __forceinline__ f32x4 mfma16h(f16x8 a, f16x8 b, f32x4 c) {
    return __builtin_amdgcn_mfma_f32_16x16x32_f16(a, b, c, 0, 0, 0);
}
// async global->LDS, 16B/lane; lds must be wave-uniform base (HW adds lane*16)
__device__ __forceinline__ void async16(void* lds, const void* g) {
    __builtin_amdgcn_global_load_lds(
        (const __attribute__((address_space(1))) u32*)g,
        (__attribute__((address_space(3))) u32*)lds, 16, 0, 0);
}

// ---------------------------------------------------------------------------
// Packed fp16 format: per 64-elem logical row, a 128B record of 8 x 16B
// blocks XOR-swizzled: element e of row r lives at ((e>>3)^(r&7))*16+(e&7)*2.
//
// KEY PERMUTATION (attn): within each wave's 32-key slice, key kt*16+q*4+r
// is stored at slot q*8+kt*4+r.  With V rows and l-flags permuted by this
// sigma, the MFMA C-layout P values (key=quad*4+r per kt) ARE the PV
// B-operand fragment (k-slot quad*8+j) in-register -> P never touches LDS.
// ---------------------------------------------------------------------------

// x [4096][1024] fp32 -> Xp [m][kc=16][128B]; emits slot-permuted fp16 flags
__global__ __launch_bounds__(256) void pack_x(const float* __restrict__ X,
                                              uchar* __restrict__ P,
                                              const int* __restrict__ M,
                                              _Float16* __restrict__ FM16)
{
    int id = blockIdx.x * 256 + threadIdx.x;       // 4096*128
    int m = id >> 7, g = id & 127;
    int kc = g >> 3, b = g & 7;
    float v[8];
    *(float4*)&v[0] = *(const float4*)&X[(size_t)m * HDIM + kc * 64 + b * 8];
    *(float4*)&v[4] = *(const float4*)&X[(size_t)m * HDIM + kc * 64 + b * 8 + 4];
    __align__(16) _Float16 h[8];
    #pragma unroll
    for (int i = 0; i < 8; i++) h[i] = (_Float16)v[i];
    size_t base = ((size_t)(m * 16 + kc)) * 128 + (size_t)((b ^ (m & 7)) * 16);
    *(uint4*)(P + base) = *(const uint4*)h;
    if (id < S_LEN) {
        int c = id >> 7, k128 = id & 127;
        int w = k128 >> 5, k32 = k128 & 31;
        int q = (k32 >> 2) & 3, kt = k32 >> 4, r = k32 & 3;
        FM16[c * 128 + w * 32 + q * 8 + kt * 4 + r] =
            (_Float16)((M[id] == 0) ? 0.0f : 1.0f);
    }
}

// All 4 weight matrices [1024 k][1024 n] fp32 -> fp16 B^T rows [n][kc=16][128B]
__global__ __launch_bounds__(256) void pack_w4(
    const float* __restrict__ W0, const float* __restrict__ W1,
    const float* __restrict__ W2, const float* __restrict__ W3,
    uchar* __restrict__ P)
{
    int id = blockIdx.x * 256 + threadIdx.x;       // 4*128*1024
    int wsel = id >> 17;
    int lid  = id & 131071;
    int g = lid >> 10, n = lid & 1023;
    int kc = g >> 3, b = g & 7;
    const float* W = (wsel == 0) ? W0 : (wsel == 1) ? W1 : (wsel == 2) ? W2 : W3;
    uchar* dst = P + (size_t)wsel * 2097152;
    float v[8];
    #pragma unroll
    for (int j = 0; j < 8; j++)
        v[j] = W[(size_t)(kc * 64 + b * 8 + j) * HDIM + n];
    __align__(16) _Float16 h[8];
    #pragma unroll
    for (int i = 0; i < 8; i++) h[i] = (_Float16)v[i];
    size_t base = ((size_t)(n * 16 + kc)) * 128 + (size_t)((b ^ (n & 7)) * 16);
    *(uint4*)(dst + base) = *(const uint4*)h;
}

// ---------------------------------------------------------------------------
// Single-fp16 MFMA GEMM, single-barrier double-buffered (unchanged).
// ---------------------------------------------------------------------------
__global__ __launch_bounds__(256) void gemm_f16(
    const uchar* __restrict__ Ap, const uchar* __restrict__ Bp,
    float* __restrict__ C, int head_major)
{
    __shared__ __align__(16) uchar AB[65536];
    const int t = threadIdx.x, lane = t & 63, w = t >> 6;
    const int quad = lane >> 4, l15 = lane & 15, x7 = l15 & 7;
    const int m0 = blockIdx.y * 128, n0 = blockIdx.x * 128;
    const int wm = (w >> 1) * 64, wn = (w & 1) * 64;

    f32x4 acc[4][4];
    const f32x4 zero4 = {0.0f, 0.0f, 0.0f, 0.0f};
    #pragma unroll
    for (int mt = 0; mt < 4; mt++)
        #pragma unroll
        for (int nt = 0; nt < 4; nt++) acc[mt][nt] = zero4;

    #pragma unroll
    for (int i = 0; i < 4; i++) {
        int idx = i * 256 + t;
        int row = idx >> 3, blk = idx & 7;
        int ldso = (idx & ~63) * 16;
        async16(AB + ldso,         Ap + ((size_t)((m0 + row) * 16 + 0)) * 128 + blk * 16);
        async16(AB + 16384 + ldso, Bp + ((size_t)((n0 + row) * 16 + 0)) * 128 + blk * 16);
    }

    for (int kc = 0; kc < 16; kc++) {
        uchar* As = AB + (kc & 1) * 32768;
        uchar* Bs = As + 16384;
        __syncthreads();
        if (kc + 1 < 16) {
            uchar* An = AB + ((kc + 1) & 1) * 32768;
            #pragma unroll
            for (int i = 0; i < 4; i++) {
                int idx = i * 256 + t;
                int row = idx >> 3, blk = idx & 7;
                int ldso = (idx & ~63) * 16;
                async16(An + ldso,
                        Ap + ((size_t)((m0 + row) * 16 + kc + 1)) * 128 + blk * 16);
                async16(An + 16384 + ldso,
                        Bp + ((size_t)((n0 + row) * 16 + kc + 1)) * 128 + blk * 16);
            }
        }
        #pragma unroll
        for (int ks = 0; ks < 2; ks++) {
            const int phys = ((ks * 4 + quad) ^ x7) * 16;
            f16x8 ah[4];
            #pragma unroll
            for (int mt = 0; mt < 4; mt++)
                ah[mt] = *(const f16x8*)(As + (size_t)(wm + mt * 16 + l15) * 128 + phys);
            #pragma unroll
            for (int nt = 0; nt < 4; nt++) {
                f16x8 bh = *(const f16x8*)(Bs + (size_t)(wn + nt * 16 + l15) * 128 + phys);
                #pragma unroll
                for (int mt = 0; mt < 4; mt++)
                    acc[mt][nt] = mfma16h(ah[mt], bh, acc[mt][nt]);
            }
        }
    }

    #pragma unroll
    for (int mt = 0; mt < 4; mt++)
        #pragma unroll
        for (int nt = 0; nt < 4; nt++)
            #pragma unroll
            for (int r = 0; r < 4; r++) {
                int m = m0 + wm + mt * 16 + quad * 4 + r;
                int n = n0 + wn + nt * 16 + l15;
                float val = acc[mt][nt][r];
                if (head_major) {
                    int hh = n >> 6, d = n & 63;
                    C[((size_t)hh * S_LEN + m) * HD + d] = val;
                } else {
                    C[(size_t)m * HDIM + n] = val;
                }
            }
}

// ---------------------------------------------------------------------------
// RoPE + pack -> fp16 single, 128B rows (Q scaled 0.125*log2e)
// ---------------------------------------------------------------------------
__global__ __launch_bounds__(256) void rope_pack(const float* __restrict__ QKVf,
                                                 uchar* __restrict__ Qg,
                                                 uchar* __restrict__ Kg)
{
    int id = blockIdx.x * 256 + threadIdx.x;   // 2*16*4096*8
    int g  = id & 7;
    int s  = (id >> 3) & (S_LEN - 1);
    int hb = id >> 15;
    const float* src = QKVf + (size_t)hb * (S_LEN * HD) + (size_t)s * HD + g * 8;
    float v[8];
    *(float4*)&v[0] = *(const float4*)&src[0];
    *(float4*)&v[4] = *(const float4*)&src[4];

    const float L32 = 13.287712379549449f / 32.0f;
    float out[8];
    #pragma unroll
    for (int u = 0; u < 4; u++) {
        int de = g * 8 + 2 * u;
        float ae = (float)s * exp2f(-(float)(de & 31) * L32);
        float ao = (float)s * exp2f(-(float)((de + 1) & 31) * L32);
        float ce = __cosf(ae), se = __sinf(ae);
        float co = __cosf(ao), so = __sinf(ao);
        float xe = v[2 * u], xo = v[2 * u + 1];
        out[2 * u]     = xe * ce - xo * se;
        out[2 * u + 1] = xo * co + xe * so;
    }
    const bool isQ = hb < 16;
    const float scale = isQ ? 0.18033688011112042f : 1.0f;  // 0.125*log2e
    __align__(16) _Float16 h[8];
    #pragma unroll
    for (int i = 0; i < 8; i++) h[i] = (_Float16)(out[i] * scale);
    uchar* dst = (isQ ? Qg : Kg);
    size_t base = ((size_t)((hb & 15) * S_LEN + s)) * 128 + (size_t)((g ^ (s & 7)) * 16);
    *(uint4*)(dst + base) = *(const uint4*)h;
}

// ---------------------------------------------------------------------------
// V pack: fp32 head-major -> fp16 transposed 16KB tiles [head][32][64d][slots],
// key rows SLOT-PERMUTED (sigma: key kt*16+q*4+r -> slot q*8+kt*4+r within
// each 32-key wave span). Masked keys zeroed.
// ---------------------------------------------------------------------------
__global__ __launch_bounds__(256) void v_pack(const float* __restrict__ Vf,
                                              const int* __restrict__ M,
                                              uchar* __restrict__ Vg)
{
    int id = blockIdx.x * 256 + threadIdx.x;   // 16*32*16*64
    int d    = id & 63;
    int kg   = (id >> 6) & 15;
    int kc2  = (id >> 10) & 31;
    int head = id >> 15;
    __align__(16) _Float16 hv[8];
    #pragma unroll
    for (int j = 0; j < 8; j++) {
        int key = kc2 * 128 + kg * 8 + j;
        float x = Vf[(size_t)head * (S_LEN * HD) + (size_t)key * HD + d];
        hv[j] = (M[key] == 0) ? (_Float16)0.0f : (_Float16)x;
    }
    // keys kg*8 .. kg*8+7 -> two 4-key granules at permuted slots
    int wv  = kg >> 2;               // wave slice
    int kgm = kg & 3;
    int kt  = kgm >> 1;
    int qA  = (kgm * 2) & 3;
    int qB  = (kgm * 2 + 1) & 3;
    int slotA = wv * 32 + qA * 8 + kt * 4;   // granule j=0..3
    int slotB = wv * 32 + qB * 8 + kt * 4;   // granule j=4..7
    size_t row = ((size_t)(head * 32 + kc2)) * 16384 + (size_t)d * 256;
    *(ushort4*)(Vg + row + (size_t)(((slotA >> 3) ^ (d & 7)) * 16 + (slotA & 7) * 2))
        = *(const ushort4*)&hv[0];
    *(ushort4*)(Vg + row + (size_t)(((slotB >> 3) ^ (d & 7)) * 16 + (slotB & 7) * 2))
        = *(const ushort4*)&hv[4];
}

// ---------------------------------------------------------------------------
// attn9: barrier-free wave pipeline, P entirely in registers.
// S^T = K*Q^T; p = 2^s (fixed-max, mask via zeroed V + flag-MFMA l).
// pkrtz-packed P values are, by construction (sigma-permuted V/flags),
// exactly the PV B-operand fragment -> no P LDS round-trip at all.
// LDS/chunk: K DMA+read, V DMA+read only. waitcnt: top vmcnt(8),
// pre-PV vmcnt(4); last step peeled (4,0). launch_bounds(256,2) - (256,3)
// spills (R10: WRITE_SIZE 8->285MB).
// ---------------------------------------------------------------------------
#define ISSUE_K(CC, KB)                                                        \
  {                                                                            \
    const uchar* ks_ = kgb + (size_t)(CC) * 16384;                             \
    async16((KB),        ks_ + l16);                                           \
    async16((KB) + 1024, ks_ + 1024 + l16);                                    \
    async16((KB) + 2048, ks_ + 2048 + l16);                                    \
    async16((KB) + 3072, ks_ + 3072 + l16);                                    \
  }
#define ISSUE_V(CC)                                                            \
  {                                                                            \
    const uchar* vs_ = vgb + (size_t)(CC) * 16384;                             \
    async16(VB,        vs_ + voff);                                            \
    async16(VB + 1024, vs_ + 4096 + voff);                                     \
    async16(VB + 2048, vs_ + 8192 + voff);                                     \
    async16(VB + 3072, vs_ + 12288 + voff);                                    \
  }

#define ATTN_STEP(CC, KB, TOPC, MIDC, FLG)                                     \
  {                                                                            \
    asm volatile("s_waitcnt vmcnt(" TOPC ")" ::: "memory");                    \
    f32x4 s0[4], s1[4];                                                        \
    _Pragma("unroll")                                                          \
    for (int qt = 0; qt < 4; qt++) { s0[qt] = zero4; s1[qt] = zero4; }         \
    _Pragma("unroll")                                                          \
    for (int ks = 0; ks < 2; ks++) {                                           \
      const int phys_ = ((ks * 4 + quad) ^ x7) * 16;                           \
      f16x8 kf0 = *(const f16x8*)((KB) + (size_t)l15 * 128 + phys_);           \
      f16x8 kf1 = *(const f16x8*)((KB) + (size_t)(16 + l15) * 128 + phys_);    \
      _Pragma("unroll")                                                        \
      for (int qt = 0; qt < 4; qt++) {                                         \
        s0[qt] = mfma16h(kf0, qf[qt][ks], s0[qt]);                             \
        s1[qt] = mfma16h(kf1, qf[qt][ks], s1[qt]);                             \
      }                                                                        \
    }                                                                          \
    f16x8 pb[4];                                                               \
    _Pragma("unroll")                                                          \
    for (int qt = 0; qt < 4; qt++) {                                           \
      h16x2 c01 = __builtin_amdgcn_cvt_pkrtz(exp2f(s0[qt][0]), exp2f(s0[qt][1])); \
      h16x2 c23 = __builtin_amdgcn_cvt_pkrtz(exp2f(s0[qt][2]), exp2f(s0[qt][3])); \
      h16x2 c45 = __builtin_amdgcn_cvt_pkrtz(exp2f(s1[qt][0]), exp2f(s1[qt][1])); \
      h16x2 c67 = __builtin_amdgcn_cvt_pkrtz(exp2f(s1[qt][2]), exp2f(s1[qt][3])); \
      uint4 pw;                                                                \
      pw.x = __builtin_bit_cast(u32, c01);                                     \
      pw.y = __builtin_bit_cast(u32, c23);                                     \
      pw.z = __builtin_bit_cast(u32, c45);                                     \
      pw.w = __builtin_bit_cast(u32, c67);                                     \
      pb[qt] = __builtin_bit_cast(f16x8, pw);                                  \
    }                                                                          \
    asm volatile("s_waitcnt vmcnt(" MIDC ")" ::: "memory");                    \
    {                                                                          \
      _Pragma("unroll")                                                        \
      for (int dt = 0; dt < 4; dt++) {                                         \
        f16x8 va = *(const f16x8*)(VB + (size_t)(dt * 16 + l15) * 64 + vrd);   \
        _Pragma("unroll")                                                      \
        for (int qt = 0; qt < 4; qt++)                                         \
          o[dt][qt] = mfma16h(va, pb[qt], o[dt][qt]);                          \
      }                                                                        \
      _Pragma("unroll")                                                        \
      for (int qt = 0; qt < 4; qt++)                                           \
        lacc[qt] = mfma16h((FLG), pb[qt], lacc[qt]);                           \
    }                                                                          \
    asm volatile("s_waitcnt lgkmcnt(0)" ::: "memory");                         \
    if ((CC) + 1 < 32) ISSUE_V((CC) + 1);                                      \
    if ((CC) + 2 < 32) {                                                       \
      ISSUE_K((CC) + 2, KB);                                                   \
      (FLG) = *(const f16x8*)(fmw + (size_t)((CC) + 2) * 256);                 \
    }                                                                          \
  }

__global__ __launch_bounds__(256, 2) void attn9(
    const uchar* __restrict__ Qg, const uchar* __restrict__ Kg,
    const uchar* __restrict__ Vg, const uchar* __restrict__ fm16,
    uchar* __restrict__ CTXp)
{
    __shared__ __align__(16) uchar arena[49152];   // 4 waves x [K0|K1|V] 4KB
    __shared__ float Lsh[4][64];
    __shared__ float Lfin[64];
    float* Os = (float*)arena;                     // merge overlay (after loop)

    const int t    = threadIdx.x;
    const int lane = t & 63;
    const int w    = t >> 6;
    const int quad = lane >> 4;
    const int l15  = lane & 15;
    const int x7   = l15 & 7;
    const int hh   = blockIdx.y;
    const int m0   = blockIdx.x * 64;

    const uchar* qgb = Qg + (size_t)hh * (S_LEN * 128);
    const uchar* kgb = Kg + (size_t)hh * (S_LEN * 128) + (size_t)w * 4096;
    const uchar* vgb = Vg + (size_t)hh * 32 * 16384;
    const uchar* fmw = fm16 + w * 64 + quad * 16;

    uchar* WB = arena + w * 12288;
    uchar* K0 = WB;
    uchar* K1 = WB + 4096;
    uchar* VB = WB + 8192;

    const int l16 = lane * 16;
    const int vphys = ((w * 4 + ((lane & 3) ^ ((lane >> 2) & 3))) ^ ((lane >> 2) & 7));
    const int voff  = (lane >> 2) * 256 + vphys * 16;
    const int vrd   = (quad ^ (l15 & 3)) * 16;

    // ---- Q fragments -> registers, once ----
    f16x8 qf[4][2];
    #pragma unroll
    for (int qt = 0; qt < 4; qt++)
        #pragma unroll
        for (int ks = 0; ks < 2; ks++)
            qf[qt][ks] = *(const f16x8*)(qgb + (size_t)(m0 + qt * 16 + l15) * 128 +
                                         (size_t)(((ks * 4 + quad) ^ x7) * 16));

    f32x4 o[4][4], lacc[4];
    const f32x4 zero4 = {0.0f, 0.0f, 0.0f, 0.0f};
    #pragma unroll
    for (int dt = 0; dt < 4; dt++)
        #pragma unroll
        for (int qt = 0; qt < 4; qt++) o[dt][qt] = zero4;
    #pragma unroll
    for (int qt = 0; qt < 4; qt++) lacc[qt] = zero4;

    // ---- prologue ----
    ISSUE_K(0, K0);
    ISSUE_V(0);
    f16x8 flagA = *(const f16x8*)(fmw);
    f16x8 flagB = *(const f16x8*)(fmw + 256);
    ISSUE_K(1, K1);

    for (int c = 0; c < 30; c += 2) {
        ATTN_STEP(c,     K0, "8", "4", flagA);
        ATTN_STEP(c + 1, K1, "8", "4", flagB);
    }
    ATTN_STEP(30, K0, "8", "4", flagA);
    ATTN_STEP(31, K1, "4", "0", flagB);

    // ---- l finalize: lane holds full slice sum (key-dim summed by MFMA) ----
    __syncthreads();                 // all waves done; arena reusable
    if (quad == 0) {
        #pragma unroll
        for (int qt = 0; qt < 4; qt++)
            Lsh[w][qt * 16 + l15] = lacc[qt][0];
    }
    __syncthreads();
    if (t < 64)
        Lfin[t] = Lsh[0][t] + Lsh[1][t] + Lsh[2][t] + Lsh[3][t];
    __syncthreads();

    // ---- o merge: plain sum across waves ----
    for (int wv = 0; wv < 4; wv++) {
        if (w == wv) {
            #pragma unroll
            for (int dt = 0; dt < 4; dt++)
                #pragma unroll
                for (int qt = 0; qt < 4; qt++)
                    #pragma unroll
                    for (int r = 0; r < 4; r++) {
                        int q = qt * 16 + l15;
                        int d = dt * 16 + quad * 4 + r;
                        float val = o[dt][qt][r];
                        if (wv == 0) Os[q * 68 + d] = val;
                        else         Os[q * 68 + d] += val;
                    }
        }
        __syncthreads();
    }

    // ---- epilogue: ctx packed fp16, kc = head (feeds Wo GEMM) ----
    #pragma unroll
    for (int i = 0; i < 4; i++) {
        int idx = t + 256 * i;
        int q   = idx >> 4;
        int c4  = (idx & 15) * 4;
        float inv = 1.0f / Lfin[q];
        float4 v = *(const float4*)&Os[q * 68 + c4];
        int m = m0 + q;
        __align__(8) _Float16 h[4];
        h[0] = (_Float16)(v.x * inv);
        h[1] = (_Float16)(v.y * inv);
        h[2] = (_Float16)(v.z * inv);
        h[3] = (_Float16)(v.w * inv);
        size_t base = ((size_t)(m * 16 + hh)) * 128 +
                      (size_t)((((c4 >> 3) ^ (m & 7))) * 16) + (c4 & 7) * 2;
        *(ushort4*)(CTXp + base) = *(const ushort4*)h;
    }
}

// ---------------------------------------------------------------------------
extern "C" void kernel_launch(void* const* d_in, const int* in_sizes, int n_in,
                              void* d_out, int out_size, void* d_ws, size_t ws_size,
                              hipStream_t stream)
{
    const float* x   = (const float*)d_in[0];
    const float* Wq  = (const float*)d_in[1];
    const float* Wk  = (const float*)d_in[2];
    const float* Wv  = (const float*)d_in[3];
    const float* Wo  = (const float*)d_in[4];
    const int* amask = (const int*)d_in[5];
    float* out = (float*)d_out;
    float* ws  = (float*)d_ws;

    // byte-offset workspace map:
    //   QKVf  fp32 [48][4096][64]   bytes [0, 50331648)
    //   Xp    fp16 packed x (8.4MB) bytes [50331648, 58720256)  later = Qg
    //   Wt4   fp16 packed W^T x4    bytes [58720256, 67108864)  (2MB each)
    //   Vg    fp16 V tiles (8.4MB)  bytes [67108864, 75497472)
    //   Fm16  fp16 flags (8KB)      bytes [75497472, 75505664)
    //   Kg    = bytes [33554432, 41943040)   (over Vf, dead after v_pack)
    //   CTXp  = bytes [0, 8388608)           (over Qf, dead after rope)
    float* QKVf = ws;
    uchar* Xp   = (uchar*)ws + 50331648;
    uchar* Wt4  = (uchar*)ws + 58720256;
    uchar* Vg   = (uchar*)ws + 67108864;
    _Float16* Fm16 = (_Float16*)((uchar*)ws + 75497472);
    uchar* Qg   = Xp;
    uchar* Kg   = (uchar*)ws + 33554432;
    uchar* CTXp = (uchar*)ws;

    dim3 blk(256);

    pack_x<<<2048, blk, 0, stream>>>(x, Xp, amask, Fm16);
    pack_w4<<<2048, blk, 0, stream>>>(Wq, Wk, Wv, Wo, Wt4);

    // fused QKV projection: N = 3072, head-major out (heads 0..47)
    gemm_f16<<<dim3(24, 32), blk, 0, stream>>>(Xp, Wt4, QKVf, 1);

    // V pack BEFORE rope (Kg aliases Vf region); masked rows zeroed, slots permuted
    v_pack<<<2048, blk, 0, stream>>>(QKVf + 8388608, amask, Vg);
    rope_pack<<<4096, blk, 0, stream>>>(QKVf, Qg, Kg);

    attn9<<<dim3(S_LEN / 64, NHEADS), blk, 0, stream>>>(Qg, Kg, Vg,
                                                        (const uchar*)Fm16, CTXp);

    // output projection: N = 1024, row-major out (Wo at Wt4 + 3*2MB)
    gemm_f16<<<dim3(8, 32), blk, 0, stream>>>(CTXp, Wt4 + 6291456, out, 0);
}